// Round 2
// baseline (616.639 us; speedup 1.0000x reference)
//
#include <hip/hip_runtime.h>
#include <hip/hip_bf16.h>
#include <math.h>

// Problem: N=4, S=2048, E=1024, H=16, D=64. Causal masked unscaled attention
// with per-head-dim (64x64) projections. Output f32.
// All intermediates f16 (not bf16): unscaled QK^T exponentiates S-errors, and
// f16's 10 mantissa bits cut dS 4x vs bf16 (R1 fix: absmax 0.125 -> ~0.03).
// ws layout: Qp[64][2048][64] f16 | Kp[64][2048][64] f16 | Vt[64][64][2048] f16
//   = 3 * 16 MiB = 50,331,648 bytes required.

#define NB  4
#define SEQ 2048
#define HD  16
#define DH  64
#define NH  (NB*HD)

typedef _Float16 half8 __attribute__((ext_vector_type(8)));
typedef float    f32x4 __attribute__((ext_vector_type(4)));

// ---------------- Q/K projection: out[(n,h),s,e] = sum_d in[n,s,h,d] * W[d,e]
__global__ __launch_bounds__(256) void proj_qk_kernel(
    const float* __restrict__ q_in, const float* __restrict__ k_in,
    const float* __restrict__ Wq,   const float* __restrict__ Wk,
    _Float16* __restrict__ Qp, _Float16* __restrict__ Kp)
{
  __shared__ float Wl[64*64];   // transposed: Wl[e][d]
  __shared__ float inl[64*64];  // inl[s_local][d]
  const float* in  = blockIdx.y ? k_in : q_in;
  const float* W   = blockIdx.y ? Wk   : Wq;
  _Float16* outp = blockIdx.y ? Kp : Qp;

  int t  = threadIdx.x;
  int b  = blockIdx.x;                 // (n, h, s-block)
  int n  = b >> 9;
  int h  = (b >> 5) & 15;
  int s0 = (b & 31) * 64;

  #pragma unroll
  for (int i = 0; i < 16; ++i) {
    int idx = i*256 + t;
    Wl[(idx & 63)*64 + (idx >> 6)] = W[idx];  // transpose W into LDS
    inl[idx] = in[((size_t)(n*SEQ + s0 + (idx >> 6))*HD + h)*DH + (idx & 63)];
  }
  __syncthreads();

  int e  = t & 63;
  int sw = t >> 6;
  const float4* wv = (const float4*)(Wl + e*64);
  float4 wreg[16];
  #pragma unroll
  for (int i = 0; i < 16; ++i) wreg[i] = wv[i];

  for (int j = 0; j < 16; ++j) {
    int s = sw*16 + j;
    const float4* rv = (const float4*)(inl + s*64);  // broadcast reads
    float acc = 0.f;
    #pragma unroll
    for (int i = 0; i < 16; ++i) {
      float4 a = rv[i];
      acc += a.x*wreg[i].x + a.y*wreg[i].y + a.z*wreg[i].z + a.w*wreg[i].w;
    }
    outp[((size_t)(n*HD + h)*SEQ + s0 + s)*DH + e] = (_Float16)acc;
  }
}

// ---------------- V projection + transpose: Vt[(n,h),d,s]
__global__ __launch_bounds__(256) void proj_v_kernel(
    const float* __restrict__ v_in, const float* __restrict__ Wv,
    _Float16* __restrict__ Vt)
{
  __shared__ float Wl[64*64];
  __shared__ float inl[64*64];
  __shared__ _Float16 outl[64*65];  // padded for transpose read

  int t  = threadIdx.x;
  int b  = blockIdx.x;
  int n  = b >> 9;
  int h  = (b >> 5) & 15;
  int s0 = (b & 31) * 64;

  #pragma unroll
  for (int i = 0; i < 16; ++i) {
    int idx = i*256 + t;
    Wl[(idx & 63)*64 + (idx >> 6)] = Wv[idx];
    inl[idx] = v_in[((size_t)(n*SEQ + s0 + (idx >> 6))*HD + h)*DH + (idx & 63)];
  }
  __syncthreads();

  int e  = t & 63;
  int sw = t >> 6;
  const float4* wv = (const float4*)(Wl + e*64);
  float4 wreg[16];
  #pragma unroll
  for (int i = 0; i < 16; ++i) wreg[i] = wv[i];

  for (int j = 0; j < 16; ++j) {
    int s = sw*16 + j;
    const float4* rv = (const float4*)(inl + s*64);
    float acc = 0.f;
    #pragma unroll
    for (int i = 0; i < 16; ++i) {
      float4 a = rv[i];
      acc += a.x*wreg[i].x + a.y*wreg[i].y + a.z*wreg[i].z + a.w*wreg[i].w;
    }
    outl[s*65 + e] = (_Float16)acc;
  }
  __syncthreads();

  #pragma unroll
  for (int i = 0; i < 16; ++i) {
    int idx = i*256 + t;
    int d = idx >> 6, sl = idx & 63;
    Vt[((size_t)(n*HD + h)*DH + d)*SEQ + s0 + sl] = outl[sl*65 + d];
  }
}

// ---------------- Flash attention (causal, unscaled), f16 MFMA
// grid (32 q-blocks, 64 heads), 4 independent waves/block, 16 q-rows/wave.
__global__ __launch_bounds__(256) void attn_kernel(
    const _Float16* __restrict__ Qp,
    const _Float16* __restrict__ Kp,
    const _Float16* __restrict__ Vt,
    float* __restrict__ out)
{
  __shared__ __attribute__((aligned(16))) _Float16 plds_all[4*16*64];

  int nh  = blockIdx.y;
  int n   = nh >> 4, h = nh & 15;
  int w   = threadIdx.x >> 6;
  int lane = threadIdx.x & 63;
  int lr  = lane & 15;      // C-frag column / A-frag row
  int lg  = lane >> 4;      // k-chunk selector
  int q0  = blockIdx.x*64 + w*16;   // this wave's 16 q-rows

  char* plds = (char*)(plds_all + w*16*64);  // 2KB per wave, private

  const _Float16* Qbase = Qp + ((size_t)nh*SEQ + q0)*DH;
  // A-frag of Q: lane holds Q[lr][kc*32 + lg*8 + i]
  half8 qf0 = *(const half8*)(Qbase + lr*DH + lg*8);
  half8 qf1 = *(const half8*)(Qbase + lr*DH + 32 + lg*8);

  const _Float16* Kbase = Kp + (size_t)nh*SEQ*DH;
  const _Float16* Vbase = Vt + (size_t)nh*DH*SEQ;

  float m[4], lsum[4];
  f32x4 o[4] = {{0,0,0,0},{0,0,0,0},{0,0,0,0},{0,0,0,0}};
  #pragma unroll
  for (int j = 0; j < 4; ++j) { m[j] = -INFINITY; lsum[j] = 0.f; }

  const int T = q0 >> 6;  // diagonal tile index (uniform across the block)
  for (int t = 0; t <= T; ++t) {
    int kt = t*64;
    // ---- S = Q K^T  (16 x 64), C layout: row=q0+4*lg+j, col=kt+16*g+lr
    f32x4 s[4] = {{0,0,0,0},{0,0,0,0},{0,0,0,0},{0,0,0,0}};
    #pragma unroll
    for (int g = 0; g < 4; ++g) {
      const _Float16* kp = Kbase + (size_t)(kt + 16*g + lr)*DH + lg*8;
      half8 kb0 = *(const half8*)kp;
      half8 kb1 = *(const half8*)(kp + 32);
      s[g] = __builtin_amdgcn_mfma_f32_16x16x32_f16(qf0, kb0, s[g], 0, 0, 0);
      s[g] = __builtin_amdgcn_mfma_f32_16x16x32_f16(qf1, kb1, s[g], 0, 0, 0);
    }
    // ---- causal mask (only the diagonal tile can be partial)
    if (t == T) {
      #pragma unroll
      for (int g = 0; g < 4; ++g)
        #pragma unroll
        for (int j = 0; j < 4; ++j) {
          if (kt + 16*g + lr > q0 + 4*lg + j) s[g][j] = -1e30f;
        }
    }
    // ---- online softmax (per row = 4*lg+j; reduce over 16 lanes of the group)
    float pm[4];
    #pragma unroll
    for (int j = 0; j < 4; ++j)
      pm[j] = fmaxf(fmaxf(s[0][j], s[1][j]), fmaxf(s[2][j], s[3][j]));
    #pragma unroll
    for (int off = 1; off < 16; off <<= 1)
      #pragma unroll
      for (int j = 0; j < 4; ++j)
        pm[j] = fmaxf(pm[j], __shfl_xor(pm[j], off));

    float sc[4];
    #pragma unroll
    for (int j = 0; j < 4; ++j) {
      float mn = fmaxf(m[j], pm[j]);
      sc[j] = __expf(m[j] - mn);   // m=-inf first tile -> 0
      m[j] = mn;
    }
    #pragma unroll
    for (int g = 0; g < 4; ++g)
      #pragma unroll
      for (int j = 0; j < 4; ++j)
        s[g][j] = __expf(s[g][j] - m[j]);   // masked: exp(-1e30-.) -> 0

    float ps[4];
    #pragma unroll
    for (int j = 0; j < 4; ++j) ps[j] = s[0][j] + s[1][j] + s[2][j] + s[3][j];
    #pragma unroll
    for (int off = 1; off < 16; off <<= 1)
      #pragma unroll
      for (int j = 0; j < 4; ++j) ps[j] += __shfl_xor(ps[j], off);

    #pragma unroll
    for (int j = 0; j < 4; ++j) lsum[j] = lsum[j]*sc[j] + ps[j];
    #pragma unroll
    for (int g = 0; g < 4; ++g)
      #pragma unroll
      for (int j = 0; j < 4; ++j) o[g][j] *= sc[j];

    // ---- P (C-layout) -> LDS -> A-frag layout, XOR-swizzled rows
    #pragma unroll
    for (int g = 0; g < 4; ++g)
      #pragma unroll
      for (int j = 0; j < 4; ++j) {
        int row = 4*lg + j;
        int cb  = (16*g + lr)*2;
        *(_Float16*)(plds + row*128 + (cb ^ ((row & 7) << 4))) =
            (_Float16)s[g][j];
      }
    // ---- O += P V   (A = P from LDS, B = V from Vt, k-contiguous)
    #pragma unroll
    for (int kc = 0; kc < 2; ++kc) {
      int cb = (kc*32 + lg*8)*2;
      half8 pa = *(const half8*)(plds + lr*128 + (cb ^ ((lr & 7) << 4)));
      #pragma unroll
      for (int g = 0; g < 4; ++g) {
        const _Float16* vp =
            Vbase + (size_t)(16*g + lr)*SEQ + kt + kc*32 + lg*8;
        half8 vb = *(const half8*)vp;
        o[g] = __builtin_amdgcn_mfma_f32_16x16x32_f16(pa, vb, o[g], 0, 0, 0);
      }
    }
  }

  // ---- epilogue: normalize, write f32 out[n][row][h*64 + col]
  #pragma unroll
  for (int j = 0; j < 4; ++j) lsum[j] = 1.0f / lsum[j];
  #pragma unroll
  for (int g = 0; g < 4; ++g)
    #pragma unroll
    for (int j = 0; j < 4; ++j) {
      int row = q0 + 4*lg + j;
      int col = h*DH + 16*g + lr;
      out[((size_t)n*SEQ + row)*(HD*DH) + col] = o[g][j] * lsum[j];
    }
}

extern "C" void kernel_launch(void* const* d_in, const int* in_sizes, int n_in,
                              void* d_out, int out_size, void* d_ws, size_t ws_size,
                              hipStream_t stream) {
  (void)in_sizes; (void)n_in; (void)out_size; (void)ws_size;
  const float* value = (const float*)d_in[0];
  const float* key   = (const float*)d_in[1];
  const float* query = (const float*)d_in[2];
  // d_in[3] = mask: causal tril, hardcoded in attn_kernel
  const float* Wq = (const float*)d_in[4];
  const float* Wk = (const float*)d_in[5];
  const float* Wv = (const float*)d_in[6];

  _Float16* Qp = (_Float16*)d_ws;
  _Float16* Kp = Qp + (size_t)NH*SEQ*DH;
  _Float16* Vt = Kp + (size_t)NH*SEQ*DH;
  float* out = (float*)d_out;

  dim3 blk(256);
  proj_qk_kernel<<<dim3(2048, 2), blk, 0, stream>>>(query, key, Wq, Wk, Qp, Kp);
  proj_v_kernel<<<dim3(2048), blk, 0, stream>>>(value, Wv, Vt);
  attn_kernel<<<dim3(32, 64), blk, 0, stream>>>(Qp, Kp, Vt, out);
}

// Round 3
// 502.633 us; speedup vs baseline: 1.2268x; 1.2268x over previous
//
#include <hip/hip_runtime.h>
#include <hip/hip_bf16.h>
#include <math.h>

// Problem: N=4, S=2048, E=1024, H=16, D=64. Causal masked unscaled attention
// with per-head-dim (64x64) projections. Output f32.
// R2: attn rewrite — paired q-blocks (b, 31-b) for uniform causal work, K/V
// tiles LDS-staged once per block (shared by 4 waves x 2 q-blocks), double
// buffered via global_load_lds(16B) with counted vmcnt + raw s_barrier, and
// XOR-swizzled (pre-swizzled global source) so ds_read_b128 is conflict-free.
// ws layout: Qp[64][2048][64] f16 | Kp[64][2048][64] f16 | Vt[64][64][2048] f16

#define NB  4
#define SEQ 2048
#define HD  16
#define DH  64
#define NH  (NB*HD)

typedef _Float16 half8 __attribute__((ext_vector_type(8)));
typedef float    f32x4 __attribute__((ext_vector_type(4)));

__device__ inline void gload16(const void* g, void* l) {
  __builtin_amdgcn_global_load_lds(
      (const __attribute__((address_space(1))) void*)g,
      (__attribute__((address_space(3))) void*)l, 16, 0, 0);
}

// ---------------- Q/K projection: out[(n,h),s,e] = sum_d in[n,s,h,d] * W[d,e]
__global__ __launch_bounds__(256) void proj_qk_kernel(
    const float* __restrict__ q_in, const float* __restrict__ k_in,
    const float* __restrict__ Wq,   const float* __restrict__ Wk,
    _Float16* __restrict__ Qp, _Float16* __restrict__ Kp)
{
  __shared__ float Wl[64*64];   // transposed: Wl[e][d]
  __shared__ float inl[64*64];  // inl[s_local][d]
  const float* in  = blockIdx.y ? k_in : q_in;
  const float* W   = blockIdx.y ? Wk   : Wq;
  _Float16* outp = blockIdx.y ? Kp : Qp;

  int t  = threadIdx.x;
  int b  = blockIdx.x;                 // (n, h, s-block)
  int n  = b >> 9;
  int h  = (b >> 5) & 15;
  int s0 = (b & 31) * 64;

  #pragma unroll
  for (int i = 0; i < 16; ++i) {
    int idx = i*256 + t;
    Wl[(idx & 63)*64 + (idx >> 6)] = W[idx];  // transpose W into LDS
    inl[idx] = in[((size_t)(n*SEQ + s0 + (idx >> 6))*HD + h)*DH + (idx & 63)];
  }
  __syncthreads();

  int e  = t & 63;
  int sw = t >> 6;
  const float4* wv = (const float4*)(Wl + e*64);
  float4 wreg[16];
  #pragma unroll
  for (int i = 0; i < 16; ++i) wreg[i] = wv[i];

  for (int j = 0; j < 16; ++j) {
    int s = sw*16 + j;
    const float4* rv = (const float4*)(inl + s*64);  // broadcast reads
    float acc = 0.f;
    #pragma unroll
    for (int i = 0; i < 16; ++i) {
      float4 a = rv[i];
      acc += a.x*wreg[i].x + a.y*wreg[i].y + a.z*wreg[i].z + a.w*wreg[i].w;
    }
    outp[((size_t)(n*HD + h)*SEQ + s0 + s)*DH + e] = (_Float16)acc;
  }
}

// ---------------- V projection + transpose: Vt[(n,h),d,s]
__global__ __launch_bounds__(256) void proj_v_kernel(
    const float* __restrict__ v_in, const float* __restrict__ Wv,
    _Float16* __restrict__ Vt)
{
  __shared__ float Wl[64*64];
  __shared__ float inl[64*64];
  __shared__ _Float16 outl[64*65];  // padded for transpose read

  int t  = threadIdx.x;
  int b  = blockIdx.x;
  int n  = b >> 9;
  int h  = (b >> 5) & 15;
  int s0 = (b & 31) * 64;

  #pragma unroll
  for (int i = 0; i < 16; ++i) {
    int idx = i*256 + t;
    Wl[(idx & 63)*64 + (idx >> 6)] = Wv[idx];
    inl[idx] = v_in[((size_t)(n*SEQ + s0 + (idx >> 6))*HD + h)*DH + (idx & 63)];
  }
  __syncthreads();

  int e  = t & 63;
  int sw = t >> 6;
  const float4* wv = (const float4*)(Wl + e*64);
  float4 wreg[16];
  #pragma unroll
  for (int i = 0; i < 16; ++i) wreg[i] = wv[i];

  for (int j = 0; j < 16; ++j) {
    int s = sw*16 + j;
    const float4* rv = (const float4*)(inl + s*64);
    float acc = 0.f;
    #pragma unroll
    for (int i = 0; i < 16; ++i) {
      float4 a = rv[i];
      acc += a.x*wreg[i].x + a.y*wreg[i].y + a.z*wreg[i].z + a.w*wreg[i].w;
    }
    outl[s*65 + e] = (_Float16)acc;
  }
  __syncthreads();

  #pragma unroll
  for (int i = 0; i < 16; ++i) {
    int idx = i*256 + t;
    int d = idx >> 6, sl = idx & 63;
    Vt[((size_t)(n*HD + h)*DH + d)*SEQ + s0 + sl] = outl[sl*65 + d];
  }
}

// ---------------- Flash attention (causal, unscaled), f16 MFMA
// grid (16 q-pairs, 64 heads), 4 waves/block, each wave: 16 rows of q-block
// ba = blockIdx.x AND 16 rows of q-block bb = 31-ba (uniform 33 tile-computes
// per block). K/V tiles double-buffered in LDS, shared by all waves.
__global__ __launch_bounds__(256, 4) void attn_kernel(
    const _Float16* __restrict__ Qp,
    const _Float16* __restrict__ Kp,
    const _Float16* __restrict__ Vt,
    float* __restrict__ out)
{
  __shared__ __attribute__((aligned(16))) _Float16 Kl[2][64*64];
  __shared__ __attribute__((aligned(16))) _Float16 Vl[2][64*64];
  __shared__ __attribute__((aligned(16))) _Float16 plds_all[4*16*64];

  const int nh = blockIdx.y;
  const int n  = nh >> 4, h = nh & 15;
  const int w  = threadIdx.x >> 6;
  const int lane = threadIdx.x & 63;
  const int lr = lane & 15;      // C-frag column / A-frag row
  const int lg = lane >> 4;      // k-chunk selector

  const int ba = blockIdx.x;     // light q-block (tiles 0..ba)
  const int bb = 31 - ba;        // heavy q-block (tiles 0..bb)
  const int q0a = ba*64 + w*16;
  const int q0b = bb*64 + w*16;

  char* plds = (char*)(plds_all + w*16*64);  // 2KB per wave, private

  const _Float16* Kbase = Kp + (size_t)nh*SEQ*DH;
  const _Float16* Vbase = Vt + (size_t)nh*DH*SEQ;

  const _Float16* Qa = Qp + ((size_t)nh*SEQ + q0a)*DH;
  const _Float16* Qb = Qp + ((size_t)nh*SEQ + q0b)*DH;
  half8 qa0 = *(const half8*)(Qa + lr*DH + lg*8);
  half8 qa1 = *(const half8*)(Qa + lr*DH + 32 + lg*8);
  half8 qb0 = *(const half8*)(Qb + lr*DH + lg*8);
  half8 qb1 = *(const half8*)(Qb + lr*DH + 32 + lg*8);

  float ma[4], la[4], mb[4], lb[4];
  f32x4 oa[4] = {{0,0,0,0},{0,0,0,0},{0,0,0,0},{0,0,0,0}};
  f32x4 ob[4] = {{0,0,0,0},{0,0,0,0},{0,0,0,0},{0,0,0,0}};
  #pragma unroll
  for (int j = 0; j < 4; ++j) { ma[j] = -INFINITY; la[j] = 0.f;
                                mb[j] = -INFINITY; lb[j] = 0.f; }

  // Stage K/V tile kt into buffer buf. Linear LDS dest (global_load_lds
  // constraint), inverse-XOR-swizzled global SOURCE; reads apply same XOR.
  auto stage = [&](int buf, int kt) {
    #pragma unroll
    for (int i = 0; i < 2; ++i) {
      int u = i*256 + w*64 + lane;        // 16B-unit index 0..511
      int row = u >> 3, c = u & 7;
      int cs = c ^ (row & 7);
      gload16(Kbase + (size_t)(kt + row)*DH + (cs << 3),
              (_Float16*)&Kl[buf][0] + (size_t)(i*256 + w*64)*8);
      gload16(Vbase + (size_t)row*SEQ + kt + (cs << 3),
              (_Float16*)&Vl[buf][0] + (size_t)(i*256 + w*64)*8);
    }
  };

  auto compute = [&](int bufi, int kt, half8 qf0, half8 qf1,
                     f32x4 (&o)[4], float (&m)[4], float (&lsum)[4],
                     int q0, bool diag) {
    const char* Kb = (const char*)&Kl[bufi][0];
    const char* Vb = (const char*)&Vl[bufi][0];
    // ---- S = Q K^T, C layout: row=q0+4*lg+j, col=kt+16*g+lr
    f32x4 s[4] = {{0,0,0,0},{0,0,0,0},{0,0,0,0},{0,0,0,0}};
    #pragma unroll
    for (int g = 0; g < 4; ++g) {
      int row = 16*g + lr;
      half8 kb0 = *(const half8*)(Kb + row*128 + ((lg ^ (row & 7)) << 4));
      half8 kb1 = *(const half8*)(Kb + row*128 + (((lg + 4) ^ (row & 7)) << 4));
      s[g] = __builtin_amdgcn_mfma_f32_16x16x32_f16(qf0, kb0, s[g], 0, 0, 0);
      s[g] = __builtin_amdgcn_mfma_f32_16x16x32_f16(qf1, kb1, s[g], 0, 0, 0);
    }
    if (diag) {
      #pragma unroll
      for (int g = 0; g < 4; ++g)
        #pragma unroll
        for (int j = 0; j < 4; ++j)
          if (kt + 16*g + lr > q0 + 4*lg + j) s[g][j] = -1e30f;
    }
    // ---- online softmax (row = 4*lg+j; reduce across the 16-lane group)
    float pm[4];
    #pragma unroll
    for (int j = 0; j < 4; ++j)
      pm[j] = fmaxf(fmaxf(s[0][j], s[1][j]), fmaxf(s[2][j], s[3][j]));
    #pragma unroll
    for (int off = 1; off < 16; off <<= 1)
      #pragma unroll
      for (int j = 0; j < 4; ++j)
        pm[j] = fmaxf(pm[j], __shfl_xor(pm[j], off));

    float sc[4];
    #pragma unroll
    for (int j = 0; j < 4; ++j) {
      float mn = fmaxf(m[j], pm[j]);
      sc[j] = __expf(m[j] - mn);
      m[j] = mn;
    }
    #pragma unroll
    for (int g = 0; g < 4; ++g)
      #pragma unroll
      for (int j = 0; j < 4; ++j)
        s[g][j] = __expf(s[g][j] - m[j]);

    float ps[4];
    #pragma unroll
    for (int j = 0; j < 4; ++j) ps[j] = s[0][j] + s[1][j] + s[2][j] + s[3][j];
    #pragma unroll
    for (int off = 1; off < 16; off <<= 1)
      #pragma unroll
      for (int j = 0; j < 4; ++j) ps[j] += __shfl_xor(ps[j], off);

    #pragma unroll
    for (int j = 0; j < 4; ++j) lsum[j] = lsum[j]*sc[j] + ps[j];
    #pragma unroll
    for (int g = 0; g < 4; ++g)
      #pragma unroll
      for (int j = 0; j < 4; ++j) o[g][j] *= sc[j];

    // ---- P (C-layout) -> wave-private LDS -> A-frag layout
    #pragma unroll
    for (int g = 0; g < 4; ++g)
      #pragma unroll
      for (int j = 0; j < 4; ++j) {
        int row = 4*lg + j;
        int cb  = (16*g + lr)*2;
        *(_Float16*)(plds + row*128 + (cb ^ ((row & 7) << 4))) =
            (_Float16)s[g][j];
      }
    // ---- O += P V   (A = P from LDS, B = V-tile from LDS)
    #pragma unroll
    for (int kc = 0; kc < 2; ++kc) {
      int cb = (kc*32 + lg*8)*2;
      half8 pa = *(const half8*)(plds + lr*128 + (cb ^ ((lr & 7) << 4)));
      #pragma unroll
      for (int g = 0; g < 4; ++g) {
        int row = 16*g + lr;
        half8 vb = *(const half8*)
            (Vb + row*128 + (((lg + 4*kc) ^ (row & 7)) << 4));
        o[g] = __builtin_amdgcn_mfma_f32_16x16x32_f16(pa, vb, o[g], 0, 0, 0);
      }
    }
  };

  // ---- main loop: double-buffered prefetch, counted vmcnt, raw barriers
  stage(0, 0);
  int cur = 0;
  for (int t = 0; t <= bb; ++t) {
    if (t < bb) {
      stage(cur ^ 1, (t + 1)*64);
      asm volatile("s_waitcnt vmcnt(4)" ::: "memory");   // tile t landed
    } else {
      asm volatile("s_waitcnt vmcnt(0)" ::: "memory");
    }
    __builtin_amdgcn_sched_barrier(0);
    __builtin_amdgcn_s_barrier();
    __builtin_amdgcn_sched_barrier(0);

    compute(cur, t*64, qb0, qb1, ob, mb, lb, q0b, t == bb);
    if (t <= ba)
      compute(cur, t*64, qa0, qa1, oa, ma, la, q0a, t == ba);

    __builtin_amdgcn_sched_barrier(0);
    __builtin_amdgcn_s_barrier();   // all waves done reading before overwrite
    cur ^= 1;
  }

  // ---- epilogue: normalize, write f32 out[n][row][h*64 + col]
  #pragma unroll
  for (int j = 0; j < 4; ++j) { la[j] = 1.0f / la[j]; lb[j] = 1.0f / lb[j]; }
  #pragma unroll
  for (int g = 0; g < 4; ++g)
    #pragma unroll
    for (int j = 0; j < 4; ++j) {
      int col = h*DH + 16*g + lr;
      int rowa = q0a + 4*lg + j;
      int rowb = q0b + 4*lg + j;
      out[((size_t)n*SEQ + rowa)*(HD*DH) + col] = oa[g][j] * la[j];
      out[((size_t)n*SEQ + rowb)*(HD*DH) + col] = ob[g][j] * lb[j];
    }
}

extern "C" void kernel_launch(void* const* d_in, const int* in_sizes, int n_in,
                              void* d_out, int out_size, void* d_ws, size_t ws_size,
                              hipStream_t stream) {
  (void)in_sizes; (void)n_in; (void)out_size; (void)ws_size;
  const float* value = (const float*)d_in[0];
  const float* key   = (const float*)d_in[1];
  const float* query = (const float*)d_in[2];
  // d_in[3] = mask: causal tril, hardcoded in attn_kernel
  const float* Wq = (const float*)d_in[4];
  const float* Wk = (const float*)d_in[5];
  const float* Wv = (const float*)d_in[6];

  _Float16* Qp = (_Float16*)d_ws;
  _Float16* Kp = Qp + (size_t)NH*SEQ*DH;
  _Float16* Vt = Kp + (size_t)NH*SEQ*DH;
  float* out = (float*)d_out;

  dim3 blk(256);
  proj_qk_kernel<<<dim3(2048, 2), blk, 0, stream>>>(query, key, Wq, Wk, Qp, Kp);
  proj_v_kernel<<<dim3(2048), blk, 0, stream>>>(value, Wv, Vt);
  attn_kernel<<<dim3(16, 64), blk, 0, stream>>>(Qp, Kp, Vt, out);
}

// Round 4
// 162.738 us; speedup vs baseline: 3.7892x; 3.0886x over previous
//
#include <hip/hip_runtime.h>
#include <hip/hip_bf16.h>
#include <math.h>

// N=4, S=2048, E=1024, H=16, D=64. Causal unscaled attention + 64x64 per-head
// projections. Output f32.
// R3: (a) attn spill fix — no lambdas (R2's ref-array lambda sent accumulators
// to scratch: 480MB scratch writes, VGPR=64); paired q-blocks (ba, 31-ba) now
// split ACROSS waves (0-3 -> ba, 4-7 -> bb) in 512-thread blocks, halving live
// state. (b) proj -> f16 MFMA (Q/K: C rows=s; V: operands swapped so C rows=e
// gives Vt[d][s] transpose for free).
// ws: Qp[64][2048][64] f16 | Kp[64][2048][64] f16 | Vt[64][64][2048] f16

#define NB  4
#define SEQ 2048
#define HD  16
#define DH  64
#define NH  (NB*HD)

typedef _Float16 half8 __attribute__((ext_vector_type(8)));
typedef float    f32x4 __attribute__((ext_vector_type(4)));

__device__ inline void gload16(const void* g, void* l) {
  __builtin_amdgcn_global_load_lds(
      (const __attribute__((address_space(1))) void*)g,
      (__attribute__((address_space(3))) void*)l, 16, 0, 0);
}

// ---------------- fused projections via MFMA (blockIdx.z: 0=Q,1=K,2=V)
__global__ __launch_bounds__(256) void proj_kernel(
    const float* __restrict__ q_in, const float* __restrict__ k_in,
    const float* __restrict__ v_in,
    const float* __restrict__ Wq, const float* __restrict__ Wk,
    const float* __restrict__ Wv,
    _Float16* __restrict__ Qp, _Float16* __restrict__ Kp,
    _Float16* __restrict__ Vt)
{
  __shared__ float Wl[64*64];   // row-major [d][e]
  const int t = threadIdx.x;
  const int which = blockIdx.z;
  const float* in = which == 0 ? q_in : (which == 1 ? k_in : v_in);
  const float* W  = which == 0 ? Wq   : (which == 1 ? Wk   : Wv);

  const int nh = blockIdx.y;
  const int n = nh >> 4, h = nh & 15;
  const int s0 = blockIdx.x * 256;

  #pragma unroll
  for (int i = 0; i < 16; ++i) Wl[i*256 + t] = W[i*256 + t];
  __syncthreads();

  const int w = t >> 6, lane = t & 63, lr = lane & 15, lg = lane >> 4;

  if (which < 2) {
    // out[(nh), s, e]: C rows = s, cols = e. B = W^T frags from LDS.
    half8 bfr[4][2];
    #pragma unroll
    for (int g = 0; g < 4; ++g)
      #pragma unroll
      for (int kc = 0; kc < 2; ++kc)
        #pragma unroll
        for (int i = 0; i < 8; ++i)
          bfr[g][kc][i] = (_Float16)Wl[(kc*32 + lg*8 + i)*64 + 16*g + lr];

    _Float16* outp = (which == 0 ? Qp : Kp) + (size_t)nh*SEQ*DH;
    #pragma unroll
    for (int pass = 0; pass < 4; ++pass) {
      int row0 = s0 + (pass*4 + w)*16;
      const float* ip = in + ((size_t)(n*SEQ + row0 + lr))*(HD*DH) + h*DH;
      float4 a0 = *(const float4*)(ip + lg*8);
      float4 a1 = *(const float4*)(ip + lg*8 + 4);
      float4 a2 = *(const float4*)(ip + 32 + lg*8);
      float4 a3 = *(const float4*)(ip + 32 + lg*8 + 4);
      half8 af0, af1;
      af0[0]=(_Float16)a0.x; af0[1]=(_Float16)a0.y; af0[2]=(_Float16)a0.z; af0[3]=(_Float16)a0.w;
      af0[4]=(_Float16)a1.x; af0[5]=(_Float16)a1.y; af0[6]=(_Float16)a1.z; af0[7]=(_Float16)a1.w;
      af1[0]=(_Float16)a2.x; af1[1]=(_Float16)a2.y; af1[2]=(_Float16)a2.z; af1[3]=(_Float16)a2.w;
      af1[4]=(_Float16)a3.x; af1[5]=(_Float16)a3.y; af1[6]=(_Float16)a3.z; af1[7]=(_Float16)a3.w;
      f32x4 c[4] = {{0,0,0,0},{0,0,0,0},{0,0,0,0},{0,0,0,0}};
      #pragma unroll
      for (int g = 0; g < 4; ++g) {
        c[g] = __builtin_amdgcn_mfma_f32_16x16x32_f16(af0, bfr[g][0], c[g], 0, 0, 0);
        c[g] = __builtin_amdgcn_mfma_f32_16x16x32_f16(af1, bfr[g][1], c[g], 0, 0, 0);
      }
      #pragma unroll
      for (int g = 0; g < 4; ++g)
        #pragma unroll
        for (int j = 0; j < 4; ++j)
          outp[(size_t)(row0 + 4*lg + j)*DH + 16*g + lr] = (_Float16)c[g][j];
    }
  } else {
    // Vt[(nh), e, s]: C rows = e, cols = s (operands swapped -> free transpose)
    half8 afr[2];
    #pragma unroll
    for (int kc = 0; kc < 2; ++kc)
      #pragma unroll
      for (int i = 0; i < 8; ++i)
        afr[kc][i] = (_Float16)Wl[(kc*32 + lg*8 + i)*64 + w*16 + lr];

    _Float16* outp = Vt + (size_t)nh*DH*SEQ;
    #pragma unroll
    for (int pass = 0; pass < 4; ++pass) {
      int sc0 = s0 + pass*64;
      f32x4 c[4] = {{0,0,0,0},{0,0,0,0},{0,0,0,0},{0,0,0,0}};
      #pragma unroll
      for (int g = 0; g < 4; ++g) {
        const float* ip = in + ((size_t)(n*SEQ + sc0 + 16*g + lr))*(HD*DH) + h*DH;
        float4 b0 = *(const float4*)(ip + lg*8);
        float4 b1 = *(const float4*)(ip + lg*8 + 4);
        float4 b2 = *(const float4*)(ip + 32 + lg*8);
        float4 b3 = *(const float4*)(ip + 32 + lg*8 + 4);
        half8 bf0, bf1;
        bf0[0]=(_Float16)b0.x; bf0[1]=(_Float16)b0.y; bf0[2]=(_Float16)b0.z; bf0[3]=(_Float16)b0.w;
        bf0[4]=(_Float16)b1.x; bf0[5]=(_Float16)b1.y; bf0[6]=(_Float16)b1.z; bf0[7]=(_Float16)b1.w;
        bf1[0]=(_Float16)b2.x; bf1[1]=(_Float16)b2.y; bf1[2]=(_Float16)b2.z; bf1[3]=(_Float16)b2.w;
        bf1[4]=(_Float16)b3.x; bf1[5]=(_Float16)b3.y; bf1[6]=(_Float16)b3.z; bf1[7]=(_Float16)b3.w;
        c[g] = __builtin_amdgcn_mfma_f32_16x16x32_f16(afr[0], bf0, c[g], 0, 0, 0);
        c[g] = __builtin_amdgcn_mfma_f32_16x16x32_f16(afr[1], bf1, c[g], 0, 0, 0);
      }
      #pragma unroll
      for (int g = 0; g < 4; ++g)
        #pragma unroll
        for (int j = 0; j < 4; ++j)
          outp[(size_t)(w*16 + 4*lg + j)*SEQ + sc0 + 16*g + lr] = (_Float16)c[g][j];
    }
  }
}

// ---------------- Flash attention (causal, unscaled), f16 MFMA
// grid (16 q-pairs, 64 heads), 512 threads = 8 waves: waves 0-3 -> q-block ba,
// waves 4-7 -> q-block bb=31-ba. K/V tiles double-buffered in LDS, swizzled.
__global__ __launch_bounds__(512) void attn_kernel(
    const _Float16* __restrict__ Qp,
    const _Float16* __restrict__ Kp,
    const _Float16* __restrict__ Vt,
    float* __restrict__ out)
{
  __shared__ __attribute__((aligned(16))) _Float16 Kl[2][64*64];
  __shared__ __attribute__((aligned(16))) _Float16 Vl[2][64*64];
  __shared__ __attribute__((aligned(16))) _Float16 plds_all[8*16*64];

  const int nh = blockIdx.y;
  const int n  = nh >> 4, h = nh & 15;
  const int tid = threadIdx.x;
  const int w = tid >> 6;
  const int lane = tid & 63;
  const int lr = lane & 15;
  const int lg = lane >> 4;

  const int ba = blockIdx.x;
  const int bb = 31 - ba;
  const int myb = (w < 4) ? ba : bb;
  const int q0  = myb*64 + (w & 3)*16;
  const int myT = myb;          // this wave's diagonal tile

  char* plds = (char*)(plds_all + w*1024);   // 2KB wave-private

  const _Float16* Kbase = Kp + (size_t)nh*SEQ*DH;
  const _Float16* Vbase = Vt + (size_t)nh*DH*SEQ;

  const _Float16* Qb = Qp + ((size_t)nh*SEQ + q0)*DH;
  half8 qf0 = *(const half8*)(Qb + lr*DH + lg*8);
  half8 qf1 = *(const half8*)(Qb + lr*DH + 32 + lg*8);

  float m[4], l[4];
  f32x4 o[4] = {{0,0,0,0},{0,0,0,0},{0,0,0,0},{0,0,0,0}};
  #pragma unroll
  for (int j = 0; j < 4; ++j) { m[j] = -INFINITY; l[j] = 0.f; }

  // staging: thread tid stages 16B-unit (srow = tid>>3, c = tid&7) with
  // pre-swizzled global source col cs = c ^ (srow&7); LDS dest linear.
  const int srow = tid >> 3;
  const int scs  = (tid & 7) ^ (srow & 7);
  const _Float16* kgp = Kbase + (size_t)srow*DH + scs*8;
  const _Float16* vgp = Vbase + (size_t)srow*SEQ + scs*8;

  gload16(kgp, (_Float16*)&Kl[0][0] + w*512);
  gload16(vgp, (_Float16*)&Vl[0][0] + w*512);

  int cur = 0;
  for (int t = 0; t <= bb; ++t) {
    if (t < bb) {
      int kt1 = (t + 1)*64;
      gload16(kgp + (size_t)kt1*DH, (_Float16*)&Kl[cur^1][0] + w*512);
      gload16(vgp + kt1,            (_Float16*)&Vl[cur^1][0] + w*512);
      asm volatile("s_waitcnt vmcnt(2)" ::: "memory");  // tile t landed
    } else {
      asm volatile("s_waitcnt vmcnt(0)" ::: "memory");
    }
    __builtin_amdgcn_sched_barrier(0);
    __builtin_amdgcn_s_barrier();
    __builtin_amdgcn_sched_barrier(0);

    if (t <= myT) {
      const char* Kb = (const char*)&Kl[cur][0];
      const char* Vb = (const char*)&Vl[cur][0];
      const int kt = t*64;
      // ---- S = Q K^T, C: row = q0+4*lg+j, col = kt+16*g+lr
      f32x4 s4[4] = {{0,0,0,0},{0,0,0,0},{0,0,0,0},{0,0,0,0}};
      #pragma unroll
      for (int g = 0; g < 4; ++g) {
        int row = 16*g + lr;
        half8 kb0 = *(const half8*)(Kb + row*128 + ((lg ^ (row & 7)) << 4));
        half8 kb1 = *(const half8*)(Kb + row*128 + (((lg + 4) ^ (row & 7)) << 4));
        s4[g] = __builtin_amdgcn_mfma_f32_16x16x32_f16(qf0, kb0, s4[g], 0, 0, 0);
        s4[g] = __builtin_amdgcn_mfma_f32_16x16x32_f16(qf1, kb1, s4[g], 0, 0, 0);
      }
      if (t == myT) {
        #pragma unroll
        for (int g = 0; g < 4; ++g)
          #pragma unroll
          for (int j = 0; j < 4; ++j)
            if (kt + 16*g + lr > q0 + 4*lg + j) s4[g][j] = -1e30f;
      }
      // ---- online softmax (row = 4*lg+j; reduce over the 16-lane group)
      float pm[4];
      #pragma unroll
      for (int j = 0; j < 4; ++j)
        pm[j] = fmaxf(fmaxf(s4[0][j], s4[1][j]), fmaxf(s4[2][j], s4[3][j]));
      #pragma unroll
      for (int off = 1; off < 16; off <<= 1)
        #pragma unroll
        for (int j = 0; j < 4; ++j)
          pm[j] = fmaxf(pm[j], __shfl_xor(pm[j], off));

      float sc[4];
      #pragma unroll
      for (int j = 0; j < 4; ++j) {
        float mn = fmaxf(m[j], pm[j]);
        sc[j] = __expf(m[j] - mn);
        m[j] = mn;
      }
      #pragma unroll
      for (int g = 0; g < 4; ++g)
        #pragma unroll
        for (int j = 0; j < 4; ++j)
          s4[g][j] = __expf(s4[g][j] - m[j]);

      float ps[4];
      #pragma unroll
      for (int j = 0; j < 4; ++j) ps[j] = s4[0][j] + s4[1][j] + s4[2][j] + s4[3][j];
      #pragma unroll
      for (int off = 1; off < 16; off <<= 1)
        #pragma unroll
        for (int j = 0; j < 4; ++j) ps[j] += __shfl_xor(ps[j], off);

      #pragma unroll
      for (int j = 0; j < 4; ++j) l[j] = l[j]*sc[j] + ps[j];
      #pragma unroll
      for (int g = 0; g < 4; ++g)
        #pragma unroll
        for (int j = 0; j < 4; ++j) o[g][j] *= sc[j];

      // ---- P (C-layout) -> wave-private LDS -> A-frag layout
      #pragma unroll
      for (int g = 0; g < 4; ++g)
        #pragma unroll
        for (int j = 0; j < 4; ++j) {
          int row = 4*lg + j;
          int cb  = (16*g + lr)*2;
          *(_Float16*)(plds + row*128 + (cb ^ ((row & 7) << 4))) =
              (_Float16)s4[g][j];
        }
      // ---- O += P V
      #pragma unroll
      for (int kc = 0; kc < 2; ++kc) {
        int cb = (kc*32 + lg*8)*2;
        half8 pa = *(const half8*)(plds + lr*128 + (cb ^ ((lr & 7) << 4)));
        #pragma unroll
        for (int g = 0; g < 4; ++g) {
          int row = 16*g + lr;
          half8 vb = *(const half8*)
              (Vb + row*128 + (((lg + 4*kc) ^ (row & 7)) << 4));
          o[g] = __builtin_amdgcn_mfma_f32_16x16x32_f16(pa, vb, o[g], 0, 0, 0);
        }
      }
    }

    __builtin_amdgcn_sched_barrier(0);
    __builtin_amdgcn_s_barrier();   // all waves done reading before overwrite
    cur ^= 1;
  }

  // ---- epilogue
  #pragma unroll
  for (int j = 0; j < 4; ++j) l[j] = 1.0f / l[j];
  #pragma unroll
  for (int g = 0; g < 4; ++g)
    #pragma unroll
    for (int j = 0; j < 4; ++j) {
      int row = q0 + 4*lg + j;
      int col = h*DH + 16*g + lr;
      out[((size_t)n*SEQ + row)*(HD*DH) + col] = o[g][j] * l[j];
    }
}

extern "C" void kernel_launch(void* const* d_in, const int* in_sizes, int n_in,
                              void* d_out, int out_size, void* d_ws, size_t ws_size,
                              hipStream_t stream) {
  (void)in_sizes; (void)n_in; (void)out_size; (void)ws_size;
  const float* value = (const float*)d_in[0];
  const float* key   = (const float*)d_in[1];
  const float* query = (const float*)d_in[2];
  // d_in[3] = mask: causal tril, hardcoded
  const float* Wq = (const float*)d_in[4];
  const float* Wk = (const float*)d_in[5];
  const float* Wv = (const float*)d_in[6];

  _Float16* Qp = (_Float16*)d_ws;
  _Float16* Kp = Qp + (size_t)NH*SEQ*DH;
  _Float16* Vt = Kp + (size_t)NH*SEQ*DH;
  float* out = (float*)d_out;

  proj_kernel<<<dim3(8, 64, 3), 256, 0, stream>>>(query, key, value,
                                                  Wq, Wk, Wv, Qp, Kp, Vt);
  attn_kernel<<<dim3(16, 64), 512, 0, stream>>>(Qp, Kp, Vt, out);
}

// Round 6
// 127.519 us; speedup vs baseline: 4.8357x; 1.2762x over previous
//
#include <hip/hip_runtime.h>
#include <hip/hip_bf16.h>
#include <math.h>

// N=4, S=2048, E=1024, H=16, D=64. Causal unscaled attention + 64x64 per-head
// projections. Output f32.
// R4/R5: attn -> swapped-operand 32x32 MFMA. S^T = mfma(K, Q^T) puts a full
// q-row in-lane (softmax = in-lane tree + 1 shfl_xor(32)); O^T = mfma(V', P^T)
// where V's global columns are permuted (bit2<->bit3 per 64-tile, applied in
// proj_v store) so P^T B-frags are the lane's own cvt_pkrtz pairs -> P never
// leaves registers. R5: fix cvt_pkrtz return-type mismatch (__fp16x2 vs
// _Float16x2) via bit-compatible union.
// ws: Qp[64][2048][64] f16 | Kp[64][2048][64] f16 | Vt[64][64][2048] f16 (perm)

#define NB  4
#define SEQ 2048
#define HD  16
#define DH  64
#define NH  (NB*HD)

typedef _Float16 half8  __attribute__((ext_vector_type(8)));
typedef _Float16 half2  __attribute__((ext_vector_type(2)));
typedef __fp16   fp16x2 __attribute__((ext_vector_type(2)));
typedef float    f32x4  __attribute__((ext_vector_type(4)));
typedef float    f32x16 __attribute__((ext_vector_type(16)));

__device__ inline half2 pkrtz(float a, float b) {
  union { fp16x2 f; half2 h; } u;
  u.f = __builtin_amdgcn_cvt_pkrtz(a, b);
  return u.h;
}

__device__ inline void gload16(const void* g, void* l) {
  __builtin_amdgcn_global_load_lds(
      (const __attribute__((address_space(1))) void*)g,
      (__attribute__((address_space(3))) void*)l, 16, 0, 0);
}

// ---------------- fused projections via MFMA (blockIdx.z: 0=Q,1=K,2=V)
__global__ __launch_bounds__(256) void proj_kernel(
    const float* __restrict__ q_in, const float* __restrict__ k_in,
    const float* __restrict__ v_in,
    const float* __restrict__ Wq, const float* __restrict__ Wk,
    const float* __restrict__ Wv,
    _Float16* __restrict__ Qp, _Float16* __restrict__ Kp,
    _Float16* __restrict__ Vt)
{
  __shared__ float Wl[64*64];   // row-major [d][e]
  const int t = threadIdx.x;
  const int which = blockIdx.z;
  const float* in = which == 0 ? q_in : (which == 1 ? k_in : v_in);
  const float* W  = which == 0 ? Wq   : (which == 1 ? Wk   : Wv);

  const int nh = blockIdx.y;
  const int n = nh >> 4, h = nh & 15;
  const int s0 = blockIdx.x * 256;

  #pragma unroll
  for (int i = 0; i < 16; ++i) Wl[i*256 + t] = W[i*256 + t];
  __syncthreads();

  const int w = t >> 6, lane = t & 63, lr = lane & 15, lg = lane >> 4;

  if (which < 2) {
    // out[(nh), s, e]: C rows = s, cols = e. B = W^T frags from LDS.
    half8 bfr[4][2];
    #pragma unroll
    for (int g = 0; g < 4; ++g)
      #pragma unroll
      for (int kc = 0; kc < 2; ++kc)
        #pragma unroll
        for (int i = 0; i < 8; ++i)
          bfr[g][kc][i] = (_Float16)Wl[(kc*32 + lg*8 + i)*64 + 16*g + lr];

    _Float16* outp = (which == 0 ? Qp : Kp) + (size_t)nh*SEQ*DH;
    #pragma unroll
    for (int pass = 0; pass < 4; ++pass) {
      int row0 = s0 + (pass*4 + w)*16;
      const float* ip = in + ((size_t)(n*SEQ + row0 + lr))*(HD*DH) + h*DH;
      float4 a0 = *(const float4*)(ip + lg*8);
      float4 a1 = *(const float4*)(ip + lg*8 + 4);
      float4 a2 = *(const float4*)(ip + 32 + lg*8);
      float4 a3 = *(const float4*)(ip + 32 + lg*8 + 4);
      half8 af0, af1;
      af0[0]=(_Float16)a0.x; af0[1]=(_Float16)a0.y; af0[2]=(_Float16)a0.z; af0[3]=(_Float16)a0.w;
      af0[4]=(_Float16)a1.x; af0[5]=(_Float16)a1.y; af0[6]=(_Float16)a1.z; af0[7]=(_Float16)a1.w;
      af1[0]=(_Float16)a2.x; af1[1]=(_Float16)a2.y; af1[2]=(_Float16)a2.z; af1[3]=(_Float16)a2.w;
      af1[4]=(_Float16)a3.x; af1[5]=(_Float16)a3.y; af1[6]=(_Float16)a3.z; af1[7]=(_Float16)a3.w;
      f32x4 c[4] = {{0,0,0,0},{0,0,0,0},{0,0,0,0},{0,0,0,0}};
      #pragma unroll
      for (int g = 0; g < 4; ++g) {
        c[g] = __builtin_amdgcn_mfma_f32_16x16x32_f16(af0, bfr[g][0], c[g], 0, 0, 0);
        c[g] = __builtin_amdgcn_mfma_f32_16x16x32_f16(af1, bfr[g][1], c[g], 0, 0, 0);
      }
      #pragma unroll
      for (int g = 0; g < 4; ++g)
        #pragma unroll
        for (int j = 0; j < 4; ++j)
          outp[(size_t)(row0 + 4*lg + j)*DH + 16*g + lr] = (_Float16)c[g][j];
    }
  } else {
    // Vt[(nh), e, s']: C rows = e, cols = s; store col permuted within each
    // 64-tile (swap bits 2<->3) so attn's PV A-frag slots are contiguous.
    half8 afr[2];
    #pragma unroll
    for (int kc = 0; kc < 2; ++kc)
      #pragma unroll
      for (int i = 0; i < 8; ++i)
        afr[kc][i] = (_Float16)Wl[(kc*32 + lg*8 + i)*64 + w*16 + lr];

    _Float16* outp = Vt + (size_t)nh*DH*SEQ;
    #pragma unroll
    for (int pass = 0; pass < 4; ++pass) {
      int sc0 = s0 + pass*64;
      f32x4 c[4] = {{0,0,0,0},{0,0,0,0},{0,0,0,0},{0,0,0,0}};
      #pragma unroll
      for (int g = 0; g < 4; ++g) {
        const float* ip = in + ((size_t)(n*SEQ + sc0 + 16*g + lr))*(HD*DH) + h*DH;
        float4 b0 = *(const float4*)(ip + lg*8);
        float4 b1 = *(const float4*)(ip + lg*8 + 4);
        float4 b2 = *(const float4*)(ip + 32 + lg*8);
        float4 b3 = *(const float4*)(ip + 32 + lg*8 + 4);
        half8 bf0, bf1;
        bf0[0]=(_Float16)b0.x; bf0[1]=(_Float16)b0.y; bf0[2]=(_Float16)b0.z; bf0[3]=(_Float16)b0.w;
        bf0[4]=(_Float16)b1.x; bf0[5]=(_Float16)b1.y; bf0[6]=(_Float16)b1.z; bf0[7]=(_Float16)b1.w;
        bf1[0]=(_Float16)b2.x; bf1[1]=(_Float16)b2.y; bf1[2]=(_Float16)b2.z; bf1[3]=(_Float16)b2.w;
        bf1[4]=(_Float16)b3.x; bf1[5]=(_Float16)b3.y; bf1[6]=(_Float16)b3.z; bf1[7]=(_Float16)b3.w;
        c[g] = __builtin_amdgcn_mfma_f32_16x16x32_f16(afr[0], bf0, c[g], 0, 0, 0);
        c[g] = __builtin_amdgcn_mfma_f32_16x16x32_f16(afr[1], bf1, c[g], 0, 0, 0);
      }
      #pragma unroll
      for (int g = 0; g < 4; ++g)
        #pragma unroll
        for (int j = 0; j < 4; ++j) {
          int kcol = 16*g + lr;
          int pcol = (kcol & ~12) | ((kcol & 8) >> 1) | ((kcol & 4) << 1);
          outp[(size_t)(w*16 + 4*lg + j)*SEQ + sc0 + pcol] = (_Float16)c[g][j];
        }
    }
  }
}

// ---------------- Flash attention, swapped 32x32 MFMA
// grid (16, 64): 4 waves x 32 q-rows = 128-q superblock sb; KVBLK=64 dbuf.
__global__ __launch_bounds__(256) void attn_kernel(
    const _Float16* __restrict__ Qp,
    const _Float16* __restrict__ Kp,
    const _Float16* __restrict__ Vt,
    float* __restrict__ out)
{
  __shared__ __attribute__((aligned(16))) _Float16 Kl[2][64*64];
  __shared__ __attribute__((aligned(16))) _Float16 Vl[2][64*64];

  const int nh = blockIdx.y;
  const int n = nh >> 4, h = nh & 15;
  // per-CU load balancing: alternate heavy/light mapping by head group
  const int sb = ((blockIdx.y >> 4) & 1) ? (int)blockIdx.x : (15 - (int)blockIdx.x);
  const int qs = sb * 128;
  const int tid = threadIdx.x;
  const int w = tid >> 6, lane = tid & 63;
  const int lq = lane & 31, lg1 = lane >> 5;
  const int q0 = qs + w*32;
  const int q  = q0 + lq;           // this lane's q row

  const _Float16* Kbase = Kp + (size_t)nh*SEQ*DH;
  const _Float16* Vbase = Vt + (size_t)nh*DH*SEQ;

  // Q B-frags: chain c holds Q[q][16c + 8*lg1 + i]
  const _Float16* Qrow = Qp + ((size_t)nh*SEQ + q)*DH + 8*lg1;
  half8 qf[4];
  #pragma unroll
  for (int c = 0; c < 4; ++c) qf[c] = *(const half8*)(Qrow + 16*c);

  // LDS read byte-offsets (same for K and V): row-tile rt, chain c
  int roff[2][4];
  #pragma unroll
  for (int rt = 0; rt < 2; ++rt)
    #pragma unroll
    for (int c = 0; c < 4; ++c)
      roff[rt][c] = (32*rt + lq)*128 + (((2*c + lg1) ^ (lq & 7)) << 4);

  // staging: thread handles 16B units tid and tid+256 (rows srow, srow+32),
  // pre-swizzled global source column.
  const int srow = tid >> 3;
  const int scs  = (tid & 7) ^ (srow & 7);
  const _Float16* kg = Kbase + (size_t)srow*DH + scs*8;
  const _Float16* vg = Vbase + (size_t)srow*SEQ + scs*8;

  float m = -INFINITY, lsum = 0.f;
  f32x16 o0 = {0,0,0,0,0,0,0,0,0,0,0,0,0,0,0,0};
  f32x16 o1 = {0,0,0,0,0,0,0,0,0,0,0,0,0,0,0,0};

  const int Tw   = q0 >> 6;         // this wave's diagonal tile
  const int Tmax = 2*sb + 1;        // block loop bound

  gload16(kg,            &Kl[0][tid*8]);
  gload16(kg + 32*DH,    &Kl[0][(256+tid)*8]);
  gload16(vg,            &Vl[0][tid*8]);
  gload16(vg + 32*SEQ,   &Vl[0][(256+tid)*8]);

  int cur = 0;
  for (int t = 0; t <= Tmax; ++t) {
    if (t < Tmax) {
      const _Float16* kgt = kg + (size_t)(t+1)*64*DH;
      const _Float16* vgt = vg + (t+1)*64;
      _Float16* kd = &Kl[cur^1][0];
      _Float16* vd = &Vl[cur^1][0];
      gload16(kgt,          kd + tid*8);
      gload16(kgt + 32*DH,  kd + (256+tid)*8);
      gload16(vgt,          vd + tid*8);
      gload16(vgt + 32*SEQ, vd + (256+tid)*8);
      asm volatile("s_waitcnt vmcnt(4)" ::: "memory");   // tile t landed
    } else {
      asm volatile("s_waitcnt vmcnt(0)" ::: "memory");
    }
    __builtin_amdgcn_sched_barrier(0);
    __builtin_amdgcn_s_barrier();
    __builtin_amdgcn_sched_barrier(0);

    if (t <= Tw) {
      const char* Kb = (const char*)&Kl[cur][0];
      const char* Vb = (const char*)&Vl[cur][0];
      const int kt = t*64;

      // ---- S^T = K . Q^T : s0 rows k=kt+klocal, s1 rows kt+32+klocal, col=q
      f32x16 s0 = {0,0,0,0,0,0,0,0,0,0,0,0,0,0,0,0};
      f32x16 s1 = {0,0,0,0,0,0,0,0,0,0,0,0,0,0,0,0};
      #pragma unroll
      for (int c = 0; c < 4; ++c) {
        half8 ka = *(const half8*)(Kb + roff[0][c]);
        half8 kb = *(const half8*)(Kb + roff[1][c]);
        s0 = __builtin_amdgcn_mfma_f32_32x32x16_f16(ka, qf[c], s0, 0, 0, 0);
        s1 = __builtin_amdgcn_mfma_f32_32x32x16_f16(kb, qf[c], s1, 0, 0, 0);
      }
      if (t == Tw) {
        #pragma unroll
        for (int j = 0; j < 16; ++j) {
          int kl = 4*lg1 + 8*(j>>2) + (j&3);
          if (kt + kl      > q) s0[j] = -1e30f;
          if (kt + 32 + kl > q) s1[j] = -1e30f;
        }
      }
      // ---- in-lane softmax (lane owns row q), 1 cross-lane op per reduce
      float t0[8];
      #pragma unroll
      for (int j = 0; j < 8; ++j)
        t0[j] = fmaxf(fmaxf(s0[j], s0[j+8]), fmaxf(s1[j], s1[j+8]));
      float pm = fmaxf(fmaxf(fmaxf(t0[0],t0[1]), fmaxf(t0[2],t0[3])),
                       fmaxf(fmaxf(t0[4],t0[5]), fmaxf(t0[6],t0[7])));
      pm = fmaxf(pm, __shfl_xor(pm, 32));
      float mn = fmaxf(m, pm);
      float sc = __expf(m - mn);
      m = mn;
      #pragma unroll
      for (int j = 0; j < 16; ++j) {
        s0[j] = __expf(s0[j] - m);
        s1[j] = __expf(s1[j] - m);
      }
      float u0[8];
      #pragma unroll
      for (int j = 0; j < 8; ++j)
        u0[j] = (s0[j] + s0[j+8]) + (s1[j] + s1[j+8]);
      float ps = ((u0[0]+u0[1]) + (u0[2]+u0[3])) + ((u0[4]+u0[5]) + (u0[6]+u0[7]));
      ps += __shfl_xor(ps, 32);
      lsum = lsum*sc + ps;
      #pragma unroll
      for (int j = 0; j < 16; ++j) { o0[j] *= sc; o1[j] *= sc; }

      // ---- pack P to f16 pairs (lane-local; k-slot map matches permuted V)
      half2 pkA[8], pkB[8];
      #pragma unroll
      for (int jj = 0; jj < 8; ++jj) {
        pkA[jj] = pkrtz(s0[2*jj], s0[2*jj+1]);
        pkB[jj] = pkrtz(s1[2*jj], s1[2*jj+1]);
      }
      // ---- O^T += V' . P^T
      #pragma unroll
      for (int c = 0; c < 4; ++c) {
        union { half8 h; half2 p[4]; } pb;
        pb.p[0] = (c < 2) ? pkA[(c&1)*4 + 0] : pkB[(c&1)*4 + 0];
        pb.p[1] = (c < 2) ? pkA[(c&1)*4 + 1] : pkB[(c&1)*4 + 1];
        pb.p[2] = (c < 2) ? pkA[(c&1)*4 + 2] : pkB[(c&1)*4 + 2];
        pb.p[3] = (c < 2) ? pkA[(c&1)*4 + 3] : pkB[(c&1)*4 + 3];
        half8 va = *(const half8*)(Vb + roff[0][c]);
        half8 vb = *(const half8*)(Vb + roff[1][c]);
        o0 = __builtin_amdgcn_mfma_f32_32x32x16_f16(va, pb.h, o0, 0, 0, 0);
        o1 = __builtin_amdgcn_mfma_f32_32x32x16_f16(vb, pb.h, o1, 0, 0, 0);
      }
    }

    __builtin_amdgcn_sched_barrier(0);
    __builtin_amdgcn_s_barrier();   // all reads done before buffer overwrite
    cur ^= 1;
  }

  // ---- epilogue: out[n][q][h*64 + dcol], per-lane scalar 1/l
  float inv = 1.0f / lsum;
  float* orow = out + ((size_t)n*SEQ + q)*(HD*DH) + h*DH;
  #pragma unroll
  for (int j = 0; j < 16; ++j) {
    int dl = 4*lg1 + 8*(j>>2) + (j&3);
    orow[dl]      = o0[j] * inv;
    orow[32 + dl] = o1[j] * inv;
  }
}

extern "C" void kernel_launch(void* const* d_in, const int* in_sizes, int n_in,
                              void* d_out, int out_size, void* d_ws, size_t ws_size,
                              hipStream_t stream) {
  (void)in_sizes; (void)n_in; (void)out_size; (void)ws_size;
  const float* value = (const float*)d_in[0];
  const float* key   = (const float*)d_in[1];
  const float* query = (const float*)d_in[2];
  // d_in[3] = mask: causal tril, hardcoded
  const float* Wq = (const float*)d_in[4];
  const float* Wk = (const float*)d_in[5];
  const float* Wv = (const float*)d_in[6];

  _Float16* Qp = (_Float16*)d_ws;
  _Float16* Kp = Qp + (size_t)NH*SEQ*DH;
  _Float16* Vt = Kp + (size_t)NH*SEQ*DH;
  float* out = (float*)d_out;

  proj_kernel<<<dim3(8, 64, 3), 256, 0, stream>>>(query, key, value,
                                                  Wq, Wk, Wv, Qp, Kp, Vt);
  attn_kernel<<<dim3(16, 64), 256, 0, stream>>>(Qp, Kp, Vt, out);
}